// Round 7
// baseline (383.677 us; speedup 1.0000x reference)
//
#include <hip/hip_runtime.h>
#include <math.h>
#include <stdint.h>

// Problem constants
#define BB 4
#define TT 2048
#define NTOK 8192        // B*T
#define DIMD 512
#define HH 8
#define DHH 64
#define MLPD 2048
#define ADIMD 256
#define MODD 3072        // 6*DIM
#define LNEPS 1e-5f
#define LOG2E_8 0.18033688011112042f   // log2(e)/8

typedef short short8 __attribute__((ext_vector_type(8)));
typedef unsigned short ushort4v __attribute__((ext_vector_type(4)));
typedef __bf16 bf16x8 __attribute__((ext_vector_type(8)));
typedef float f32x4 __attribute__((ext_vector_type(4)));

static __device__ __forceinline__ unsigned short f2bf(float f) {
    union { float f; unsigned u; } v; v.f = f;
    unsigned r = v.u + 0x7fffu + ((v.u >> 16) & 1u);
    return (unsigned short)(r >> 16);
}
static __device__ __forceinline__ float bf2f(unsigned short u) {
    union { unsigned u; float f; } v; v.u = (unsigned)u << 16; return v.f;
}

static __device__ __forceinline__ f32x4 mfma_bf16(short8 a, short8 b, f32x4 c) {
    return __builtin_amdgcn_mfma_f32_16x16x32_bf16(
        __builtin_bit_cast(bf16x8, a), __builtin_bit_cast(bf16x8, b), c, 0, 0, 0);
}

// CK-style LDS barrier: waits DS ops only, leaves vmcnt OUTSTANDING across the
// barrier (unlike __syncthreads, which drains vmcnt(0) and kills prefetch).
static __device__ __forceinline__ void bar_lds() {
    asm volatile("s_waitcnt lgkmcnt(0)\n\ts_barrier" ::: "memory");
}

// ---------------------------------------------------------------------------
// Merged fp32->bf16 conversion: 5 weights + silu(action_emb), one launch
// ---------------------------------------------------------------------------
struct CvtArgs {
    const float* s[6];
    unsigned short* d[6];
    int cum[7];   // cumulative n4 offsets
};
__global__ __launch_bounds__(256) void cvt_all(CvtArgs a)
{
    const int i = blockIdx.x * 256 + threadIdx.x;
    if (i >= a.cum[6]) return;
    int seg = 0;
    #pragma unroll
    for (int k = 1; k < 6; k++) seg += (i >= a.cum[k]);
    const int off = i - a.cum[seg];
    float4 v = ((const float4*)a.s[seg])[off];
    if (seg == 5) {   // silu for action_emb
        v.x = v.x / (1.f + __expf(-v.x));
        v.y = v.y / (1.f + __expf(-v.y));
        v.z = v.z / (1.f + __expf(-v.z));
        v.w = v.w / (1.f + __expf(-v.w));
    }
    ushort4v o = { f2bf(v.x), f2bf(v.y), f2bf(v.z), f2bf(v.w) };
    ((ushort4v*)a.d[seg])[off] = o;
}

// ---------------------------------------------------------------------------
// bf16 MFMA NT GEMM, 2-deep register-prefetch K-loop with no-drain barriers.
// C[m,n] = epi( sum_k A[m,k]*B[n,k] ); A: MxK bf16, B: NxK bf16 row-major.
// Tile 128 x BN, BK=64, 4 waves. K must be a multiple of 128 (even # 64-tiles).
// Loads for tile t+2 issue before compute(t); staged after compute(t+1).
// EPI: 0 = bf16 store
//      2 = bf16 store gelu_exact(acc + bias[n])
//      3 = fp32 store res[m,n] + mod[m*3072+1024+n]*(acc+bias[n])
//      4 = fp32 RMW    C[m,n] + mod[m*3072+2560+n]*(acc+bias[n])
//      5 = bf16 store acc + bias[n]
// ---------------------------------------------------------------------------
template<int EPI, int BN>
__global__ __launch_bounds__(256) void gemm_bf16(
    const unsigned short* __restrict__ A, const unsigned short* __restrict__ Bw,
    const float* __restrict__ bias, const float* __restrict__ res,
    const unsigned short* __restrict__ mod,
    int M, int N, int K,
    void* __restrict__ Cv)
{
    constexpr int MT = (BN == 128) ? 4 : 2;   // per-wave m-tiles (of 16)
    constexpr int NPB = (BN == 128) ? 4 : 2;  // B staging passes per thread
    __shared__ unsigned short As[128 * 72];   // [row][k], stride 72
    __shared__ unsigned short Bs[BN * 72];

    const int tid = threadIdx.x;
    const int w = tid >> 6, lane = tid & 63;
    const int quad = lane >> 4, l16 = lane & 15;
    const int wrow = (BN == 128) ? (w >> 1) * 64 : w * 32;
    const int wcol = (BN == 128) ? (w & 1) * 64 : 0;
    const int row0 = blockIdx.y * 128, col0 = blockIdx.x * BN;

    const int srow = tid >> 3;          // 0..31
    const int skc  = (tid & 7) * 8;     // 0..56

    f32x4 acc[MT][4];
    #pragma unroll
    for (int i = 0; i < MT; i++)
        #pragma unroll
        for (int j = 0; j < 4; j++) acc[i][j] = (f32x4){0.f, 0.f, 0.f, 0.f};

    short8 a0[4], b0[NPB], a1[4], b1[NPB];

#define G_LOAD(AS_, BS_, k0_) do {                                              \
    _Pragma("unroll") for (int p = 0; p < 4; p++)                               \
        AS_[p] = *(const short8*)&A[(size_t)(row0 + srow + p * 32) * K + (k0_) + skc]; \
    _Pragma("unroll") for (int p = 0; p < NPB; p++)                             \
        BS_[p] = *(const short8*)&Bw[(size_t)(col0 + srow + p * 32) * K + (k0_) + skc]; \
} while (0)

#define G_STAGE(AS_, BS_) do {                                                  \
    _Pragma("unroll") for (int p = 0; p < 4; p++)                               \
        *(short8*)&As[(srow + p * 32) * 72 + skc] = AS_[p];                     \
    _Pragma("unroll") for (int p = 0; p < NPB; p++)                             \
        *(short8*)&Bs[(srow + p * 32) * 72 + skc] = BS_[p];                     \
} while (0)

#define G_COMPUTE() do {                                                        \
    _Pragma("unroll") for (int ks = 0; ks < 2; ks++) {                          \
        short8 af[MT], bf[4];                                                   \
        _Pragma("unroll") for (int mt = 0; mt < MT; mt++)                       \
            af[mt] = *(const short8*)&As[(wrow + mt * 16 + l16) * 72 + ks * 32 + quad * 8]; \
        _Pragma("unroll") for (int nt = 0; nt < 4; nt++)                        \
            bf[nt] = *(const short8*)&Bs[(wcol + nt * 16 + l16) * 72 + ks * 32 + quad * 8]; \
        _Pragma("unroll") for (int nt = 0; nt < 4; nt++)                        \
            _Pragma("unroll") for (int mt = 0; mt < MT; mt++)                   \
                acc[mt][nt] = mfma_bf16(af[mt], bf[nt], acc[mt][nt]);           \
    }                                                                           \
} while (0)

    const int NK = K >> 6;              // even for all call sites (4/8/32)
    G_LOAD(a0, b0, 0);
    G_LOAD(a1, b1, 64);
    G_STAGE(a0, b0);                    // waits only set-0 loads (fine vmcnt)
    bar_lds();

    for (int t = 0; t < NK; t += 2) {
        if (t + 2 < NK) G_LOAD(a0, b0, (t + 2) << 6);
        G_COMPUTE();                    // tile t
        bar_lds();
        G_STAGE(a1, b1);                // tile t+1 (loads had ~1 compute slack+)
        bar_lds();
        if (t + 3 < NK) G_LOAD(a1, b1, (t + 3) << 6);
        G_COMPUTE();                    // tile t+1
        if (t + 2 < NK) {
            bar_lds();
            G_STAGE(a0, b0);            // tile t+2 (~2 computes of slack)
            bar_lds();
        }
    }
#undef G_LOAD
#undef G_STAGE
#undef G_COMPUTE

    float* Cf = (float*)Cv;
    unsigned short* Cb = (unsigned short*)Cv;
    #pragma unroll
    for (int mt = 0; mt < MT; mt++) {
        #pragma unroll
        for (int r = 0; r < 4; r++) {
            const int row = row0 + wrow + mt * 16 + quad * 4 + r;
            #pragma unroll
            for (int nt = 0; nt < 4; nt++) {
                const int col = col0 + wcol + nt * 16 + l16;
                const size_t idx = (size_t)row * N + col;
                const float v = acc[mt][nt][r];
                if (EPI == 0) {
                    Cb[idx] = f2bf(v);
                } else if (EPI == 2) {
                    float t = v + bias[col];
                    Cb[idx] = f2bf(0.5f * t * (1.f + erff(t * 0.70710678118654752f)));
                } else if (EPI == 3) {
                    float t = v + bias[col];
                    Cf[idx] = res[idx] + bf2f(mod[(size_t)row * MODD + 1024 + col]) * t;
                } else if (EPI == 4) {
                    float t = v + bias[col];
                    Cf[idx] = Cf[idx] + bf2f(mod[(size_t)row * MODD + 2560 + col]) * t;
                } else if (EPI == 5) {
                    Cb[idx] = f2bf(v + bias[col]);
                }
            }
        }
    }
}

// ---------------------------------------------------------------------------
// adaLN: dst(bf16)[n,:] = LN(src[n,:])*(1+mod[n,scale:+512]) + mod[n,shift:+512]
// ---------------------------------------------------------------------------
__global__ __launch_bounds__(256) void adaln_ln(
    const float* __restrict__ src, const unsigned short* __restrict__ mod,
    unsigned short* __restrict__ dst, int shift_off, int scale_off)
{
    const int n = blockIdx.x;
    const int tid = threadIdx.x;
    const float* xr = src + (size_t)n * DIMD;
    float v0 = xr[tid], v1 = xr[tid + 256];
    float s = v0 + v1;
    float q = v0 * v0 + v1 * v1;
    #pragma unroll
    for (int o = 32; o > 0; o >>= 1) {
        s += __shfl_down(s, o);
        q += __shfl_down(q, o);
    }
    __shared__ float sh[8];
    __shared__ float mu_sh, rs_sh;
    const int wid = tid >> 6, lane = tid & 63;
    if (lane == 0) { sh[wid] = s; sh[wid + 4] = q; }
    __syncthreads();
    if (tid == 0) {
        float S = sh[0] + sh[1] + sh[2] + sh[3];
        float Q = sh[4] + sh[5] + sh[6] + sh[7];
        float mu = S * (1.f / DIMD);
        float var = Q * (1.f / DIMD) - mu * mu;
        mu_sh = mu;
        rs_sh = rsqrtf(var + LNEPS);
    }
    __syncthreads();
    const float mu = mu_sh, rs = rs_sh;
    const unsigned short* mrow = mod + (size_t)n * MODD;
    const size_t o0 = (size_t)n * DIMD + tid;
    dst[o0]       = f2bf((v0 - mu) * rs * (1.f + bf2f(mrow[scale_off + tid]))       + bf2f(mrow[shift_off + tid]));
    dst[o0 + 256] = f2bf((v1 - mu) * rs * (1.f + bf2f(mrow[scale_off + tid + 256])) + bf2f(mrow[shift_off + tid + 256]));
}

// ---------------------------------------------------------------------------
// MFMA flash attention v4: v3 + 2-deep KV prefetch + no-drain barriers.
// qkv: [NTOK,1536] bf16 (q/k/v at +0/+512/+1024, inner h*64+d). out bf16.
// Grid (T/64=32, H, B); 4 waves; wave = 16 q rows. K-tile = 64.
// S^T = K·Q^T: C col=lane&15 = q-row -> per-lane softmax, cross-quad shfl only.
// ---------------------------------------------------------------------------
__global__ __launch_bounds__(256, 4) void attn_mfma(
    const unsigned short* __restrict__ qkv, unsigned short* __restrict__ outb)
{
    __shared__ unsigned short Kt[64][72];     // K[kpos][d], +8 pad
    __shared__ unsigned short Vt[64][72];     // V^T: Vt[d][kpos], +8 pad
    __shared__ unsigned short Ps[4][16][72];  // per-wave P[q][kpos]

    const int qi = (TT / 64 - 1) - blockIdx.x;    // long blocks first
    const int h = blockIdx.y, b = blockIdx.z;
    const int tid = threadIdx.x;
    const int w = tid >> 6;
    const int lane = tid & 63;
    const int quad = lane >> 4;
    const int l16 = lane & 15;

    const int qw = qi * 64 + w * 16;
    const size_t tokbase = (size_t)b * TT;

    // Q fragment (B operand of S^T = K·Q^T); fold log2(e)/8 into the bf16
    short8 qf[2];
    {
        const unsigned short* qp = qkv + (tokbase + qw + l16) * 1536 + h * 64 + quad * 8;
        #pragma unroll
        for (int hd = 0; hd < 2; hd++) {
            short8 raw = *(const short8*)(qp + hd * 32);
            short8 f;
            #pragma unroll
            for (int j = 0; j < 8; j++)
                f[j] = (short)f2bf(bf2f((unsigned short)raw[j]) * LOG2E_8);
            qf[hd] = f;
        }
    }

    f32x4 Oa[4];   // [d-tile]; col=lane&15=q, row=quad*4+r=d
    float mrun = -INFINITY, lrun = 0.f;
    #pragma unroll
    for (int mt = 0; mt < 4; mt++) Oa[mt] = (f32x4){0.f, 0.f, 0.f, 0.f};

    const int nkt = qi + 1;
    const int vk0 = (tid & 31) * 2;        // k-pair this thread transposes
    const int vdb = (tid >> 5) * 8;        // d-chunk base (8 groups x 8 d)

    short8 kp0[2], vp0[2], kp1[2], vp1[2];

#define A_LOAD(KS_, VS_, kt_) do {                                              \
    const unsigned short* kb = qkv + (tokbase + (size_t)(kt_) * 64) * 1536 + 512 + h * 64; \
    _Pragma("unroll") for (int it = 0; it < 2; it++) {                          \
        const int i = tid + it * 256;                                           \
        KS_[it] = *(const short8*)(kb + (size_t)(i >> 3) * 1536 + (i & 7) * 8); \
    }                                                                           \
    const unsigned short* vb = qkv + (tokbase + (size_t)(kt_) * 64 + vk0) * 1536 + 1024 + h * 64 + vdb; \
    VS_[0] = *(const short8*)vb;                                                \
    VS_[1] = *(const short8*)(vb + 1536);                                       \
} while (0)

#define A_STAGE(KS_, VS_) do {                                                  \
    _Pragma("unroll") for (int it = 0; it < 2; it++) {                          \
        const int i = tid + it * 256;                                           \
        *(short8*)&Kt[i >> 3][(i & 7) * 8] = KS_[it];                           \
    }                                                                           \
    _Pragma("unroll") for (int j = 0; j < 8; j++) {                             \
        *(unsigned*)&Vt[vdb + j][vk0] =                                         \
            (unsigned)(unsigned short)VS_[0][j]                                 \
            | ((unsigned)(unsigned short)VS_[1][j] << 16);                      \
    }                                                                           \
} while (0)

#define A_COMPUTE(kt_) do {                                                     \
    f32x4 st[4];                                                                \
    _Pragma("unroll") for (int mk = 0; mk < 4; mk++) {                          \
        const short8 ka0 = *(const short8*)&Kt[mk * 16 + l16][quad * 8];        \
        const short8 ka1 = *(const short8*)&Kt[mk * 16 + l16][32 + quad * 8];   \
        st[mk] = (f32x4){0.f, 0.f, 0.f, 0.f};                                   \
        st[mk] = mfma_bf16(ka0, qf[0], st[mk]);                                 \
        st[mk] = mfma_bf16(ka1, qf[1], st[mk]);                                 \
    }                                                                           \
    if ((kt_) == qi) {                                                          \
        const int qpos = qw + l16;                                              \
        _Pragma("unroll") for (int mk = 0; mk < 4; mk++)                        \
            _Pragma("unroll") for (int r = 0; r < 4; r++)                       \
                if ((kt_) * 64 + mk * 16 + quad * 4 + r > qpos) st[mk][r] = -INFINITY; \
    }                                                                           \
    float tm = -INFINITY;                                                       \
    _Pragma("unroll") for (int mk = 0; mk < 4; mk++)                            \
        _Pragma("unroll") for (int r = 0; r < 4; r++) tm = fmaxf(tm, st[mk][r]);\
    tm = fmaxf(tm, __shfl_xor(tm, 16));                                         \
    tm = fmaxf(tm, __shfl_xor(tm, 32));                                         \
    const float mn = fmaxf(mrun, tm);                                           \
    const float alpha = __builtin_amdgcn_exp2f(mrun - mn);                      \
    mrun = mn;                                                                  \
    float ts = 0.f;                                                             \
    _Pragma("unroll") for (int mk = 0; mk < 4; mk++) {                          \
        const float p0 = __builtin_amdgcn_exp2f(st[mk][0] - mn);                \
        const float p1 = __builtin_amdgcn_exp2f(st[mk][1] - mn);                \
        const float p2 = __builtin_amdgcn_exp2f(st[mk][2] - mn);                \
        const float p3 = __builtin_amdgcn_exp2f(st[mk][3] - mn);                \
        ts += (p0 + p1) + (p2 + p3);                                            \
        const unsigned long long pk =                                           \
            (unsigned long long)f2bf(p0)                                        \
            | ((unsigned long long)f2bf(p1) << 16)                              \
            | ((unsigned long long)f2bf(p2) << 32)                              \
            | ((unsigned long long)f2bf(p3) << 48);                             \
        *(unsigned long long*)&Ps[w][l16][mk * 16 + quad * 4] = pk;             \
    }                                                                           \
    ts += __shfl_xor(ts, 16);                                                   \
    ts += __shfl_xor(ts, 32);                                                   \
    lrun = lrun * alpha + ts;                                                   \
    _Pragma("unroll") for (int mt = 0; mt < 4; mt++) Oa[mt] *= alpha;           \
    __threadfence_block();                                                      \
    short8 pf[2];                                                               \
    _Pragma("unroll") for (int kc = 0; kc < 2; kc++)                            \
        pf[kc] = *(const short8*)&Ps[w][l16][kc * 32 + quad * 8];               \
    _Pragma("unroll") for (int mt = 0; mt < 4; mt++)                            \
        _Pragma("unroll") for (int kc = 0; kc < 2; kc++) {                      \
            const short8 vf = *(const short8*)&Vt[mt * 16 + l16][kc * 32 + quad * 8]; \
            Oa[mt] = mfma_bf16(vf, pf[kc], Oa[mt]);                             \
        }                                                                       \
} while (0)

    // prologue: tile 0 (+ tile 1 loads in flight)
    A_LOAD(kp0, vp0, 0);
    if (nkt > 1) A_LOAD(kp1, vp1, 1);
    A_STAGE(kp0, vp0);                  // waits only set-0 loads
    bar_lds();

    int t = 0;
    while (t < nkt) {
        // parity-0 body: compute tile t; stage set1 (tile t+1); load set0 (t+2)
        if (t + 2 < nkt) A_LOAD(kp0, vp0, t + 2);
        A_COMPUTE(t);
        bar_lds();
        if (t + 1 < nkt) { A_STAGE(kp1, vp1); bar_lds(); }
        t++;
        if (t >= nkt) break;
        // parity-1 body
        if (t + 2 < nkt) A_LOAD(kp1, vp1, t + 2);
        A_COMPUTE(t);
        bar_lds();
        if (t + 1 < nkt) { A_STAGE(kp0, vp0); bar_lds(); }
        t++;
    }
#undef A_LOAD
#undef A_STAGE
#undef A_COMPUTE

    // ---- epilogue: O /= l ----  lane owns q-row
    {
        const float inv = 1.f / lrun;
        const size_t tok = tokbase + qw + l16;
        #pragma unroll
        for (int mt = 0; mt < 4; mt++) {
            const unsigned long long pk =
                (unsigned long long)f2bf(Oa[mt][0] * inv)
                | ((unsigned long long)f2bf(Oa[mt][1] * inv) << 16)
                | ((unsigned long long)f2bf(Oa[mt][2] * inv) << 32)
                | ((unsigned long long)f2bf(Oa[mt][3] * inv) << 48);
            *(unsigned long long*)&outb[tok * DIMD + h * 64 + mt * 16 + quad * 4] = pk;
        }
    }
}

// ---------------------------------------------------------------------------
extern "C" void kernel_launch(void* const* d_in, const int* in_sizes, int n_in,
                              void* d_out, int out_size, void* d_ws, size_t ws_size,
                              hipStream_t stream)
{
    (void)in_sizes; (void)n_in; (void)out_size; (void)ws_size;

    const float* x    = (const float*)d_in[0];
    const float* aemb = (const float*)d_in[1];
    const float* Wqkv = (const float*)d_in[3];
    const float* Wout = (const float*)d_in[4];
    const float* bout = (const float*)d_in[5];
    const float* W1   = (const float*)d_in[6];
    const float* b1   = (const float*)d_in[7];
    const float* W2   = (const float*)d_in[8];
    const float* b2   = (const float*)d_in[9];
    const float* Wmod = (const float*)d_in[10];
    const float* bmod = (const float*)d_in[11];

    float* out = (float*)d_out;

    // workspace layout
    char* p = (char*)d_ws;
    unsigned short* modw = (unsigned short*)p; p += (size_t)NTOK * MODD * 2;   // bf16 mod
    unsigned short* h12  = (unsigned short*)p; p += (size_t)NTOK * DIMD * 2;
    unsigned short* qkvb = (unsigned short*)p; p += (size_t)NTOK * 1536 * 2;
    unsigned short* attw = (unsigned short*)p; p += (size_t)NTOK * DIMD * 2;
    unsigned short* hid  = qkvb;        // reuses qkvb+attw (8192*2048*2 exactly)
    unsigned short* sact = (unsigned short*)p; p += (size_t)NTOK * ADIMD * 2;
    unsigned short* wq = (unsigned short*)p;   p += (size_t)1536 * 512 * 2;
    unsigned short* wo = (unsigned short*)p;   p += (size_t)512 * 512 * 2;
    unsigned short* w1 = (unsigned short*)p;   p += (size_t)2048 * 512 * 2;
    unsigned short* w2 = (unsigned short*)p;   p += (size_t)512 * 2048 * 2;
    unsigned short* wm = (unsigned short*)p;   p += (size_t)3072 * 256 * 2;

    // 0) all dtype conversions in one launch
    CvtArgs ca;
    ca.s[0] = Wqkv; ca.d[0] = wq;
    ca.s[1] = Wout; ca.d[1] = wo;
    ca.s[2] = W1;   ca.d[2] = w1;
    ca.s[3] = W2;   ca.d[3] = w2;
    ca.s[4] = Wmod; ca.d[4] = wm;
    ca.s[5] = aemb; ca.d[5] = sact;   // silu applied
    const int n4s[6] = {1536 * 512 / 4, 512 * 512 / 4, 2048 * 512 / 4,
                        512 * 2048 / 4, 3072 * 256 / 4, NTOK * ADIMD / 4};
    ca.cum[0] = 0;
    for (int i = 0; i < 6; i++) ca.cum[i + 1] = ca.cum[i] + n4s[i];
    cvt_all<<<(ca.cum[6] + 255) / 256, 256, 0, stream>>>(ca);

    // 1) mod = silu(action_emb) @ Wmod^T + bmod  (bf16 out)
    gemm_bf16<5, 128><<<dim3(MODD / 128, NTOK / 128), 256, 0, stream>>>(
        sact, wm, bmod, nullptr, nullptr, NTOK, MODD, ADIMD, modw);

    // 2) h1 = LN(x)*(1+scale1)+shift1  (bf16 out)
    adaln_ln<<<NTOK, 256, 0, stream>>>(x, modw, h12, 0, 512);

    // 3) qkv = h1 @ Wqkv^T  (bf16 out)
    gemm_bf16<0, 128><<<dim3(1536 / 128, NTOK / 128), 256, 0, stream>>>(
        h12, wq, nullptr, nullptr, nullptr, NTOK, 1536, DIMD, qkvb);

    // 4) attention (bf16 flash MFMA v4)
    attn_mfma<<<dim3(TT / 64, HH, BB), 256, 0, stream>>>(qkvb, attw);

    // 5) x_mid = x + gate1 * (attw @ Wout^T + bout)  (fp32 out -> d_out)
    gemm_bf16<3, 64><<<dim3(DIMD / 64, NTOK / 128), 256, 0, stream>>>(
        attw, wo, bout, x, modw, NTOK, DIMD, DIMD, out);

    // 6) h2 = LN(x_mid)*(1+scale2)+shift2  (bf16 out)
    adaln_ln<<<NTOK, 256, 0, stream>>>(out, modw, h12, 1536, 2048);

    // 7) hid = gelu(h2 @ W1^T + b1)  (bf16 out)
    gemm_bf16<2, 128><<<dim3(MLPD / 128, NTOK / 128), 256, 0, stream>>>(
        h12, w1, b1, nullptr, nullptr, NTOK, MLPD, DIMD, hid);

    // 8) d_out = x_mid + gate2 * (hid @ W2^T + b2)  (fp32 RMW)
    gemm_bf16<4, 64><<<dim3(DIMD / 64, NTOK / 128), 256, 0, stream>>>(
        hid, w2, b2, nullptr, modw, NTOK, DIMD, MLPD, out);
}

// Round 9
// 330.710 us; speedup vs baseline: 1.1602x; 1.1602x over previous
//
#include <hip/hip_runtime.h>
#include <math.h>
#include <stdint.h>

// Problem constants
#define BB 4
#define TT 2048
#define NTOK 8192        // B*T
#define DIMD 512
#define HH 8
#define DHH 64
#define MLPD 2048
#define ADIMD 256
#define MODD 3072        // 6*DIM
#define LNEPS 1e-5f
#define LOG2E_8 0.18033688011112042f   // log2(e)/8

typedef short short8 __attribute__((ext_vector_type(8)));
typedef unsigned short ushort4v __attribute__((ext_vector_type(4)));
typedef __bf16 bf16x8 __attribute__((ext_vector_type(8)));
typedef float f32x4 __attribute__((ext_vector_type(4)));

static __device__ __forceinline__ unsigned short f2bf(float f) {
    union { float f; unsigned u; } v; v.f = f;
    unsigned r = v.u + 0x7fffu + ((v.u >> 16) & 1u);
    return (unsigned short)(r >> 16);
}
static __device__ __forceinline__ float bf2f(unsigned short u) {
    union { unsigned u; float f; } v; v.u = (unsigned)u << 16; return v.f;
}
// pack two f32->bf16 into one dword
static __device__ __forceinline__ unsigned pk2bf(float a, float b) {
    return (unsigned)f2bf(a) | ((unsigned)f2bf(b) << 16);
}

static __device__ __forceinline__ f32x4 mfma_bf16(short8 a, short8 b, f32x4 c) {
    return __builtin_amdgcn_mfma_f32_16x16x32_bf16(
        __builtin_bit_cast(bf16x8, a), __builtin_bit_cast(bf16x8, b), c, 0, 0, 0);
}

// ---------------------------------------------------------------------------
// Merged fp32->bf16 conversion: 5 weights + silu(action_emb), one launch
// ---------------------------------------------------------------------------
struct CvtArgs {
    const float* s[6];
    unsigned short* d[6];
    int cum[7];   // cumulative n4 offsets
};
__global__ __launch_bounds__(256) void cvt_all(CvtArgs a)
{
    const int i = blockIdx.x * 256 + threadIdx.x;
    if (i >= a.cum[6]) return;
    int seg = 0;
    #pragma unroll
    for (int k = 1; k < 6; k++) seg += (i >= a.cum[k]);
    const int off = i - a.cum[seg];
    float4 v = ((const float4*)a.s[seg])[off];
    if (seg == 5) {   // silu for action_emb
        v.x = v.x / (1.f + __expf(-v.x));
        v.y = v.y / (1.f + __expf(-v.y));
        v.z = v.z / (1.f + __expf(-v.z));
        v.w = v.w / (1.f + __expf(-v.w));
    }
    uint2 o;
    o.x = pk2bf(v.x, v.y);
    o.y = pk2bf(v.z, v.w);
    ((uint2*)a.d[seg])[off] = o;
}

// ---------------------------------------------------------------------------
// bf16 MFMA NT GEMM, pipelined K-loop (R5 structure) + occupancy bounds.
// C[m,n] = epi( sum_k A[m,k]*B[n,k] ); A: MxK bf16, B: NxK bf16 row-major.
// Tile 128 x BN, BK=64, 4 waves. __launch_bounds__ min-waves/EU: 3 (BN=128,
// cap ~170 VGPR -> 3 blocks/CU) or 4 (BN=64, cap 128 -> 4 blocks/CU).
// EPI: 0 = bf16 store
//      2 = bf16 store gelu_exact(acc + bias[n])
//      3 = fp32 store res[m,n] + mod[m*3072+1024+n]*(acc+bias[n])
//      4 = fp32 RMW    C[m,n] + mod[m*3072+2560+n]*(acc+bias[n])
//      5 = bf16 store acc + bias[n]
// ---------------------------------------------------------------------------
template<int EPI, int BN>
__global__ __launch_bounds__(256, (BN == 128 ? 3 : 4)) void gemm_bf16(
    const unsigned short* __restrict__ A, const unsigned short* __restrict__ Bw,
    const float* __restrict__ bias, const float* __restrict__ res,
    const unsigned short* __restrict__ mod,
    int M, int N, int K,
    void* __restrict__ Cv)
{
    constexpr int MT = (BN == 128) ? 4 : 2;   // per-wave m-tiles (of 16)
    constexpr int NPB = (BN == 128) ? 4 : 2;  // B staging passes per thread
    __shared__ unsigned short As[128 * 72];   // [row][k], stride 72
    __shared__ unsigned short Bs[BN * 72];

    const int tid = threadIdx.x;
    const int w = tid >> 6, lane = tid & 63;
    const int quad = lane >> 4, l16 = lane & 15;
    const int wrow = (BN == 128) ? (w >> 1) * 64 : w * 32;
    const int wcol = (BN == 128) ? (w & 1) * 64 : 0;
    const int row0 = blockIdx.y * 128, col0 = blockIdx.x * BN;

    const int srow = tid >> 3;          // 0..31
    const int skc  = (tid & 7) * 8;     // 0..56

    f32x4 acc[MT][4];
    #pragma unroll
    for (int i = 0; i < MT; i++)
        #pragma unroll
        for (int j = 0; j < 4; j++) acc[i][j] = (f32x4){0.f, 0.f, 0.f, 0.f};

    short8 pA[4], pB[NPB];
    auto prefetch = [&](int k0) {
        #pragma unroll
        for (int p = 0; p < 4; p++)
            pA[p] = *(const short8*)&A[(size_t)(row0 + srow + p * 32) * K + k0 + skc];
        #pragma unroll
        for (int p = 0; p < NPB; p++)
            pB[p] = *(const short8*)&Bw[(size_t)(col0 + srow + p * 32) * K + k0 + skc];
    };
    auto stage = [&]() {
        #pragma unroll
        for (int p = 0; p < 4; p++)
            *(short8*)&As[(srow + p * 32) * 72 + skc] = pA[p];
        #pragma unroll
        for (int p = 0; p < NPB; p++)
            *(short8*)&Bs[(srow + p * 32) * 72 + skc] = pB[p];
    };

    prefetch(0);
    stage();
    __syncthreads();

    for (int k0 = 0; k0 < K; k0 += 64) {
        const bool more = (k0 + 64 < K);
        if (more) prefetch(k0 + 64);    // loads in flight during MFMAs

        #pragma unroll
        for (int ks = 0; ks < 2; ks++) {
            short8 af[MT], bf[4];
            #pragma unroll
            for (int mt = 0; mt < MT; mt++)
                af[mt] = *(const short8*)&As[(wrow + mt * 16 + l16) * 72 + ks * 32 + quad * 8];
            #pragma unroll
            for (int nt = 0; nt < 4; nt++)
                bf[nt] = *(const short8*)&Bs[(wcol + nt * 16 + l16) * 72 + ks * 32 + quad * 8];
            #pragma unroll
            for (int nt = 0; nt < 4; nt++)
                #pragma unroll
                for (int mt = 0; mt < MT; mt++)
                    acc[mt][nt] = mfma_bf16(af[mt], bf[nt], acc[mt][nt]);
        }
        __syncthreads();                // all LDS reads of this tile done
        if (more) stage();              // vmcnt wait lands here, after compute
        __syncthreads();                // staging visible
    }

    float* Cf = (float*)Cv;
    unsigned short* Cb = (unsigned short*)Cv;
    #pragma unroll
    for (int mt = 0; mt < MT; mt++) {
        #pragma unroll
        for (int r = 0; r < 4; r++) {
            const int row = row0 + wrow + mt * 16 + quad * 4 + r;
            #pragma unroll
            for (int nt = 0; nt < 4; nt++) {
                const int col = col0 + wcol + nt * 16 + l16;
                const size_t idx = (size_t)row * N + col;
                const float v = acc[mt][nt][r];
                if (EPI == 0) {
                    Cb[idx] = f2bf(v);
                } else if (EPI == 2) {
                    float t = v + bias[col];
                    Cb[idx] = f2bf(0.5f * t * (1.f + erff(t * 0.70710678118654752f)));
                } else if (EPI == 3) {
                    float t = v + bias[col];
                    Cf[idx] = res[idx] + bf2f(mod[(size_t)row * MODD + 1024 + col]) * t;
                } else if (EPI == 4) {
                    float t = v + bias[col];
                    Cf[idx] = Cf[idx] + bf2f(mod[(size_t)row * MODD + 2560 + col]) * t;
                } else if (EPI == 5) {
                    Cb[idx] = f2bf(v + bias[col]);
                }
            }
        }
    }
}

// ---------------------------------------------------------------------------
// adaLN: dst(bf16)[n,:] = LN(src[n,:])*(1+mod[n,scale:+512]) + mod[n,shift:+512]
// ---------------------------------------------------------------------------
__global__ __launch_bounds__(256) void adaln_ln(
    const float* __restrict__ src, const unsigned short* __restrict__ mod,
    unsigned short* __restrict__ dst, int shift_off, int scale_off)
{
    const int n = blockIdx.x;
    const int tid = threadIdx.x;
    const float* xr = src + (size_t)n * DIMD;
    float v0 = xr[tid], v1 = xr[tid + 256];
    float s = v0 + v1;
    float q = v0 * v0 + v1 * v1;
    #pragma unroll
    for (int o = 32; o > 0; o >>= 1) {
        s += __shfl_down(s, o);
        q += __shfl_down(q, o);
    }
    __shared__ float sh[8];
    __shared__ float mu_sh, rs_sh;
    const int wid = tid >> 6, lane = tid & 63;
    if (lane == 0) { sh[wid] = s; sh[wid + 4] = q; }
    __syncthreads();
    if (tid == 0) {
        float S = sh[0] + sh[1] + sh[2] + sh[3];
        float Q = sh[4] + sh[5] + sh[6] + sh[7];
        float mu = S * (1.f / DIMD);
        float var = Q * (1.f / DIMD) - mu * mu;
        mu_sh = mu;
        rs_sh = rsqrtf(var + LNEPS);
    }
    __syncthreads();
    const float mu = mu_sh, rs = rs_sh;
    const unsigned short* mrow = mod + (size_t)n * MODD;
    const size_t o0 = (size_t)n * DIMD + tid;
    dst[o0]       = f2bf((v0 - mu) * rs * (1.f + bf2f(mrow[scale_off + tid]))       + bf2f(mrow[shift_off + tid]));
    dst[o0 + 256] = f2bf((v1 - mu) * rs * (1.f + bf2f(mrow[scale_off + tid + 256])) + bf2f(mrow[shift_off + tid + 256]));
}

// ---------------------------------------------------------------------------
// MFMA flash attention v3 (R6 structure) + paired bf16 packing.
// qkv: [NTOK,1536] bf16 (q/k/v at +0/+512/+1024, inner h*64+d). out bf16 [NTOK,512].
// Grid (T/64=32, H, B) = 1024 blocks; 4 waves; wave = 16 q rows. K-tile = 64.
// S^T = K·Q^T: C col=lane&15 = q-row -> per-lane softmax, cross-quad shfl only.
// ---------------------------------------------------------------------------
__global__ __launch_bounds__(256, 4) void attn_mfma(
    const unsigned short* __restrict__ qkv, unsigned short* __restrict__ outb)
{
    __shared__ unsigned short Kt[64][72];     // K[kpos][d], +8 pad
    __shared__ unsigned short Vt[64][72];     // V^T: Vt[d][kpos], +8 pad
    __shared__ unsigned short Ps[4][16][72];  // per-wave P[q][kpos]

    const int qi = (TT / 64 - 1) - blockIdx.x;    // long blocks first
    const int h = blockIdx.y, b = blockIdx.z;
    const int tid = threadIdx.x;
    const int w = tid >> 6;
    const int lane = tid & 63;
    const int quad = lane >> 4;
    const int l16 = lane & 15;

    const int qw = qi * 64 + w * 16;
    const size_t tokbase = (size_t)b * TT;

    // Q fragment (B operand of S^T = K·Q^T); fold log2(e)/8 into the bf16
    short8 qf[2];
    {
        const unsigned short* qp = qkv + (tokbase + qw + l16) * 1536 + h * 64 + quad * 8;
        #pragma unroll
        for (int hd = 0; hd < 2; hd++) {
            short8 raw = *(const short8*)(qp + hd * 32);
            short8 f;
            #pragma unroll
            for (int j = 0; j < 8; j++)
                f[j] = (short)f2bf(bf2f((unsigned short)raw[j]) * LOG2E_8);
            qf[hd] = f;
        }
    }

    f32x4 Oa[4];   // [d-tile]; col=lane&15=q, row=quad*4+r=d
    float mrun = -INFINITY, lrun = 0.f;
    #pragma unroll
    for (int mt = 0; mt < 4; mt++) Oa[mt] = (f32x4){0.f, 0.f, 0.f, 0.f};

    const int nkt = qi + 1;
    const int vk0 = (tid & 31) * 2;        // k-pair this thread transposes
    const int vdb = (tid >> 5) * 8;        // d-chunk base (8 groups x 8 d)

    short8 kpre[2], vpre[2];
    auto prefetchKV = [&](int kt) {
        const unsigned short* kb = qkv + (tokbase + (size_t)kt * 64) * 1536 + 512 + h * 64;
        #pragma unroll
        for (int it = 0; it < 2; it++) {
            const int i = tid + it * 256;
            kpre[it] = *(const short8*)(kb + (size_t)(i >> 3) * 1536 + (i & 7) * 8);
        }
        const unsigned short* vb = qkv + (tokbase + (size_t)kt * 64 + vk0) * 1536 + 1024 + h * 64 + vdb;
        vpre[0] = *(const short8*)vb;
        vpre[1] = *(const short8*)(vb + 1536);
    };
    auto storeKV = [&]() {
        #pragma unroll
        for (int it = 0; it < 2; it++) {
            const int i = tid + it * 256;
            *(short8*)&Kt[i >> 3][(i & 7) * 8] = kpre[it];
        }
        #pragma unroll
        for (int j = 0; j < 8; j++) {
            *(unsigned*)&Vt[vdb + j][vk0] =
                (unsigned)(unsigned short)vpre[0][j]
                | ((unsigned)(unsigned short)vpre[1][j] << 16);
        }
    };

    prefetchKV(0);
    storeKV();
    __syncthreads();

    for (int kt = 0; kt < nkt; kt++) {
        const bool haveNext = (kt + 1 < nkt);
        if (haveNext) prefetchKV(kt + 1);   // loads in flight during compute

        // ---- S^T = K·Q^T ----  A = K (rows = kpos), B = Q^T
        f32x4 st[4];
        #pragma unroll
        for (int mk = 0; mk < 4; mk++) {
            const short8 a0 = *(const short8*)&Kt[mk * 16 + l16][quad * 8];
            const short8 a1 = *(const short8*)&Kt[mk * 16 + l16][32 + quad * 8];
            st[mk] = (f32x4){0.f, 0.f, 0.f, 0.f};
            st[mk] = mfma_bf16(a0, qf[0], st[mk]);
            st[mk] = mfma_bf16(a1, qf[1], st[mk]);
        }
        if (kt == qi) {   // diagonal tile: causal mask (k > q -> -inf)
            const int qpos = qw + l16;
            #pragma unroll
            for (int mk = 0; mk < 4; mk++)
                #pragma unroll
                for (int r = 0; r < 4; r++)
                    if (kt * 64 + mk * 16 + quad * 4 + r > qpos) st[mk][r] = -INFINITY;
        }
        // ---- per-lane softmax (q fixed per lane); cross-quad reduce only ----
        float tm = -INFINITY;
        #pragma unroll
        for (int mk = 0; mk < 4; mk++)
            #pragma unroll
            for (int r = 0; r < 4; r++) tm = fmaxf(tm, st[mk][r]);
        tm = fmaxf(tm, __shfl_xor(tm, 16));
        tm = fmaxf(tm, __shfl_xor(tm, 32));
        const float mn = fmaxf(mrun, tm);
        const float alpha = __builtin_amdgcn_exp2f(mrun - mn);
        mrun = mn;
        float ts = 0.f;
        #pragma unroll
        for (int mk = 0; mk < 4; mk++) {
            const float p0 = __builtin_amdgcn_exp2f(st[mk][0] - mn);
            const float p1 = __builtin_amdgcn_exp2f(st[mk][1] - mn);
            const float p2 = __builtin_amdgcn_exp2f(st[mk][2] - mn);
            const float p3 = __builtin_amdgcn_exp2f(st[mk][3] - mn);
            ts += (p0 + p1) + (p2 + p3);
            const unsigned long long pk =
                (unsigned long long)pk2bf(p0, p1)
                | ((unsigned long long)pk2bf(p2, p3) << 32);
            *(unsigned long long*)&Ps[w][l16][mk * 16 + quad * 4] = pk;
        }
        ts += __shfl_xor(ts, 16);
        ts += __shfl_xor(ts, 32);
        lrun = lrun * alpha + ts;
        #pragma unroll
        for (int mt = 0; mt < 4; mt++) Oa[mt] *= alpha;
        __threadfence_block();   // own Ps stores -> reads ordering

        // ---- O^T += V^T·P^T ----  A = V^T, B = P^T (read from P[q][k])
        short8 pf[2];
        #pragma unroll
        for (int kc = 0; kc < 2; kc++)
            pf[kc] = *(const short8*)&Ps[w][l16][kc * 32 + quad * 8];
        #pragma unroll
        for (int mt = 0; mt < 4; mt++)
            #pragma unroll
            for (int kc = 0; kc < 2; kc++) {
                const short8 vf = *(const short8*)&Vt[mt * 16 + l16][kc * 32 + quad * 8];
                Oa[mt] = mfma_bf16(vf, pf[kc], Oa[mt]);
            }

        __syncthreads();            // all LDS reads of tile kt done
        if (haveNext) storeKV();    // implicit vmcnt waits on prefetched regs
        __syncthreads();            // staging visible
    }

    // ---- epilogue: O /= l ----  lane owns q-row
    {
        const float inv = 1.f / lrun;
        const size_t tok = tokbase + qw + l16;
        #pragma unroll
        for (int mt = 0; mt < 4; mt++) {
            const unsigned long long pk =
                (unsigned long long)pk2bf(Oa[mt][0] * inv, Oa[mt][1] * inv)
                | ((unsigned long long)pk2bf(Oa[mt][2] * inv, Oa[mt][3] * inv) << 32);
            *(unsigned long long*)&outb[tok * DIMD + h * 64 + mt * 16 + quad * 4] = pk;
        }
    }
}

// ---------------------------------------------------------------------------
extern "C" void kernel_launch(void* const* d_in, const int* in_sizes, int n_in,
                              void* d_out, int out_size, void* d_ws, size_t ws_size,
                              hipStream_t stream)
{
    (void)in_sizes; (void)n_in; (void)out_size; (void)ws_size;

    const float* x    = (const float*)d_in[0];
    const float* aemb = (const float*)d_in[1];
    const float* Wqkv = (const float*)d_in[3];
    const float* Wout = (const float*)d_in[4];
    const float* bout = (const float*)d_in[5];
    const float* W1   = (const float*)d_in[6];
    const float* b1   = (const float*)d_in[7];
    const float* W2   = (const float*)d_in[8];
    const float* b2   = (const float*)d_in[9];
    const float* Wmod = (const float*)d_in[10];
    const float* bmod = (const float*)d_in[11];

    float* out = (float*)d_out;

    // workspace layout
    char* p = (char*)d_ws;
    unsigned short* modw = (unsigned short*)p; p += (size_t)NTOK * MODD * 2;   // bf16 mod
    unsigned short* h12  = (unsigned short*)p; p += (size_t)NTOK * DIMD * 2;
    unsigned short* qkvb = (unsigned short*)p; p += (size_t)NTOK * 1536 * 2;
    unsigned short* attw = (unsigned short*)p; p += (size_t)NTOK * DIMD * 2;
    unsigned short* hid  = qkvb;        // reuses qkvb+attw (8192*2048*2 exactly)
    unsigned short* sact = (unsigned short*)p; p += (size_t)NTOK * ADIMD * 2;
    unsigned short* wq = (unsigned short*)p;   p += (size_t)1536 * 512 * 2;
    unsigned short* wo = (unsigned short*)p;   p += (size_t)512 * 512 * 2;
    unsigned short* w1 = (unsigned short*)p;   p += (size_t)2048 * 512 * 2;
    unsigned short* w2 = (unsigned short*)p;   p += (size_t)512 * 2048 * 2;
    unsigned short* wm = (unsigned short*)p;   p += (size_t)3072 * 256 * 2;

    // 0) all dtype conversions in one launch
    CvtArgs ca;
    ca.s[0] = Wqkv; ca.d[0] = wq;
    ca.s[1] = Wout; ca.d[1] = wo;
    ca.s[2] = W1;   ca.d[2] = w1;
    ca.s[3] = W2;   ca.d[3] = w2;
    ca.s[4] = Wmod; ca.d[4] = wm;
    ca.s[5] = aemb; ca.d[5] = sact;   // silu applied
    const int n4s[6] = {1536 * 512 / 4, 512 * 512 / 4, 2048 * 512 / 4,
                        512 * 2048 / 4, 3072 * 256 / 4, NTOK * ADIMD / 4};
    ca.cum[0] = 0;
    for (int i = 0; i < 6; i++) ca.cum[i + 1] = ca.cum[i] + n4s[i];
    cvt_all<<<(ca.cum[6] + 255) / 256, 256, 0, stream>>>(ca);

    // 1) mod = silu(action_emb) @ Wmod^T + bmod  (bf16 out)
    gemm_bf16<5, 128><<<dim3(MODD / 128, NTOK / 128), 256, 0, stream>>>(
        sact, wm, bmod, nullptr, nullptr, NTOK, MODD, ADIMD, modw);

    // 2) h1 = LN(x)*(1+scale1)+shift1  (bf16 out)
    adaln_ln<<<NTOK, 256, 0, stream>>>(x, modw, h12, 0, 512);

    // 3) qkv = h1 @ Wqkv^T  (bf16 out)
    gemm_bf16<0, 128><<<dim3(1536 / 128, NTOK / 128), 256, 0, stream>>>(
        h12, wq, nullptr, nullptr, nullptr, NTOK, 1536, DIMD, qkvb);

    // 4) attention (bf16 flash MFMA v3)
    attn_mfma<<<dim3(TT / 64, HH, BB), 256, 0, stream>>>(qkvb, attw);

    // 5) x_mid = x + gate1 * (attw @ Wout^T + bout)  (fp32 out -> d_out)
    gemm_bf16<3, 64><<<dim3(DIMD / 64, NTOK / 128), 256, 0, stream>>>(
        attw, wo, bout, x, modw, NTOK, DIMD, DIMD, out);

    // 6) h2 = LN(x_mid)*(1+scale2)+shift2  (bf16 out)
    adaln_ln<<<NTOK, 256, 0, stream>>>(out, modw, h12, 1536, 2048);

    // 7) hid = gelu(h2 @ W1^T + b1)  (bf16 out)
    gemm_bf16<2, 128><<<dim3(MLPD / 128, NTOK / 128), 256, 0, stream>>>(
        h12, w1, b1, nullptr, nullptr, NTOK, MLPD, DIMD, hid);

    // 8) d_out = x_mid + gate2 * (hid @ W2^T + b2)  (fp32 RMW)
    gemm_bf16<4, 64><<<dim3(DIMD / 64, NTOK / 128), 256, 0, stream>>>(
        hid, w2, b2, nullptr, modw, NTOK, DIMD, MLPD, out);
}

// Round 10
// 320.919 us; speedup vs baseline: 1.1956x; 1.0305x over previous
//
#include <hip/hip_runtime.h>
#include <math.h>
#include <stdint.h>

// Problem constants
#define BB 4
#define TT 2048
#define NTOK 8192        // B*T
#define DIMD 512
#define HH 8
#define DHH 64
#define MLPD 2048
#define ADIMD 256
#define MODD 3072        // 6*DIM
#define LNEPS 1e-5f
#define LOG2E_8 0.18033688011112042f   // log2(e)/8
#define PBLK 4224        // partial block floats: 64*64 O + 128 (m,l)

typedef short short8 __attribute__((ext_vector_type(8)));
typedef unsigned short ushort4v __attribute__((ext_vector_type(4)));
typedef __bf16 bf16x8 __attribute__((ext_vector_type(8)));
typedef float f32x4 __attribute__((ext_vector_type(4)));

static __device__ __forceinline__ unsigned short f2bf(float f) {
    union { float f; unsigned u; } v; v.f = f;
    unsigned r = v.u + 0x7fffu + ((v.u >> 16) & 1u);
    return (unsigned short)(r >> 16);
}
static __device__ __forceinline__ float bf2f(unsigned short u) {
    union { unsigned u; float f; } v; v.u = (unsigned)u << 16; return v.f;
}
static __device__ __forceinline__ unsigned pk2bf(float a, float b) {
    return (unsigned)f2bf(a) | ((unsigned)f2bf(b) << 16);
}

static __device__ __forceinline__ f32x4 mfma_bf16(short8 a, short8 b, f32x4 c) {
    return __builtin_amdgcn_mfma_f32_16x16x32_bf16(
        __builtin_bit_cast(bf16x8, a), __builtin_bit_cast(bf16x8, b), c, 0, 0, 0);
}

// ---------------------------------------------------------------------------
// Merged fp32->bf16 conversion: 5 weights + silu(action_emb), one launch
// ---------------------------------------------------------------------------
struct CvtArgs {
    const float* s[6];
    unsigned short* d[6];
    int cum[7];
};
__global__ __launch_bounds__(256) void cvt_all(CvtArgs a)
{
    const int i = blockIdx.x * 256 + threadIdx.x;
    if (i >= a.cum[6]) return;
    int seg = 0;
    #pragma unroll
    for (int k = 1; k < 6; k++) seg += (i >= a.cum[k]);
    const int off = i - a.cum[seg];
    float4 v = ((const float4*)a.s[seg])[off];
    if (seg == 5) {
        v.x = v.x / (1.f + __expf(-v.x));
        v.y = v.y / (1.f + __expf(-v.y));
        v.z = v.z / (1.f + __expf(-v.z));
        v.w = v.w / (1.f + __expf(-v.w));
    }
    uint2 o;
    o.x = pk2bf(v.x, v.y);
    o.y = pk2bf(v.z, v.w);
    ((uint2*)a.d[seg])[off] = o;
}

// ---------------------------------------------------------------------------
// bf16 MFMA NT GEMM (R9 structure, LDS stride 72 -> 76: staging writes drop
// from 8-way to <=4-way bank conflicts; frag reads stay ~2-way/free).
// EPI: 0 bf16; 2 bf16 gelu(acc+bias); 3 fp32 res+gate1*(acc+bias);
//      4 fp32 RMW +gate2*(acc+bias); 5 bf16 acc+bias
// ---------------------------------------------------------------------------
template<int EPI, int BN>
__global__ __launch_bounds__(256, (BN == 128 ? 3 : 4)) void gemm_bf16(
    const unsigned short* __restrict__ A, const unsigned short* __restrict__ Bw,
    const float* __restrict__ bias, const float* __restrict__ res,
    const unsigned short* __restrict__ mod,
    int M, int N, int K,
    void* __restrict__ Cv)
{
    constexpr int MT = (BN == 128) ? 4 : 2;
    constexpr int NPB = (BN == 128) ? 4 : 2;
    __shared__ unsigned short As[128 * 76];
    __shared__ unsigned short Bs[BN * 76];

    const int tid = threadIdx.x;
    const int w = tid >> 6, lane = tid & 63;
    const int quad = lane >> 4, l16 = lane & 15;
    const int wrow = (BN == 128) ? (w >> 1) * 64 : w * 32;
    const int wcol = (BN == 128) ? (w & 1) * 64 : 0;
    const int row0 = blockIdx.y * 128, col0 = blockIdx.x * BN;

    const int srow = tid >> 3;
    const int skc  = (tid & 7) * 8;

    f32x4 acc[MT][4];
    #pragma unroll
    for (int i = 0; i < MT; i++)
        #pragma unroll
        for (int j = 0; j < 4; j++) acc[i][j] = (f32x4){0.f, 0.f, 0.f, 0.f};

    short8 pA[4], pB[NPB];
    auto prefetch = [&](int k0) {
        #pragma unroll
        for (int p = 0; p < 4; p++)
            pA[p] = *(const short8*)&A[(size_t)(row0 + srow + p * 32) * K + k0 + skc];
        #pragma unroll
        for (int p = 0; p < NPB; p++)
            pB[p] = *(const short8*)&Bw[(size_t)(col0 + srow + p * 32) * K + k0 + skc];
    };
    auto stage = [&]() {
        #pragma unroll
        for (int p = 0; p < 4; p++)
            *(short8*)&As[(srow + p * 32) * 76 + skc] = pA[p];
        #pragma unroll
        for (int p = 0; p < NPB; p++)
            *(short8*)&Bs[(srow + p * 32) * 76 + skc] = pB[p];
    };

    prefetch(0);
    stage();
    __syncthreads();

    for (int k0 = 0; k0 < K; k0 += 64) {
        const bool more = (k0 + 64 < K);
        if (more) prefetch(k0 + 64);

        #pragma unroll
        for (int ks = 0; ks < 2; ks++) {
            short8 af[MT], bf[4];
            #pragma unroll
            for (int mt = 0; mt < MT; mt++)
                af[mt] = *(const short8*)&As[(wrow + mt * 16 + l16) * 76 + ks * 32 + quad * 8];
            #pragma unroll
            for (int nt = 0; nt < 4; nt++)
                bf[nt] = *(const short8*)&Bs[(wcol + nt * 16 + l16) * 76 + ks * 32 + quad * 8];
            #pragma unroll
            for (int nt = 0; nt < 4; nt++)
                #pragma unroll
                for (int mt = 0; mt < MT; mt++)
                    acc[mt][nt] = mfma_bf16(af[mt], bf[nt], acc[mt][nt]);
        }
        __syncthreads();
        if (more) stage();
        __syncthreads();
    }

    float* Cf = (float*)Cv;
    unsigned short* Cb = (unsigned short*)Cv;
    #pragma unroll
    for (int mt = 0; mt < MT; mt++) {
        #pragma unroll
        for (int r = 0; r < 4; r++) {
            const int row = row0 + wrow + mt * 16 + quad * 4 + r;
            #pragma unroll
            for (int nt = 0; nt < 4; nt++) {
                const int col = col0 + wcol + nt * 16 + l16;
                const size_t idx = (size_t)row * N + col;
                const float v = acc[mt][nt][r];
                if (EPI == 0) {
                    Cb[idx] = f2bf(v);
                } else if (EPI == 2) {
                    float t = v + bias[col];
                    Cb[idx] = f2bf(0.5f * t * (1.f + erff(t * 0.70710678118654752f)));
                } else if (EPI == 3) {
                    float t = v + bias[col];
                    Cf[idx] = res[idx] + bf2f(mod[(size_t)row * MODD + 1024 + col]) * t;
                } else if (EPI == 4) {
                    float t = v + bias[col];
                    Cf[idx] = Cf[idx] + bf2f(mod[(size_t)row * MODD + 2560 + col]) * t;
                } else if (EPI == 5) {
                    Cb[idx] = f2bf(v + bias[col]);
                }
            }
        }
    }
}

// ---------------------------------------------------------------------------
// adaLN (unchanged)
// ---------------------------------------------------------------------------
__global__ __launch_bounds__(256) void adaln_ln(
    const float* __restrict__ src, const unsigned short* __restrict__ mod,
    unsigned short* __restrict__ dst, int shift_off, int scale_off)
{
    const int n = blockIdx.x;
    const int tid = threadIdx.x;
    const float* xr = src + (size_t)n * DIMD;
    float v0 = xr[tid], v1 = xr[tid + 256];
    float s = v0 + v1;
    float q = v0 * v0 + v1 * v1;
    #pragma unroll
    for (int o = 32; o > 0; o >>= 1) {
        s += __shfl_down(s, o);
        q += __shfl_down(q, o);
    }
    __shared__ float sh[8];
    __shared__ float mu_sh, rs_sh;
    const int wid = tid >> 6, lane = tid & 63;
    if (lane == 0) { sh[wid] = s; sh[wid + 4] = q; }
    __syncthreads();
    if (tid == 0) {
        float S = sh[0] + sh[1] + sh[2] + sh[3];
        float Q = sh[4] + sh[5] + sh[6] + sh[7];
        float mu = S * (1.f / DIMD);
        float var = Q * (1.f / DIMD) - mu * mu;
        mu_sh = mu;
        rs_sh = rsqrtf(var + LNEPS);
    }
    __syncthreads();
    const float mu = mu_sh, rs = rs_sh;
    const unsigned short* mrow = mod + (size_t)n * MODD;
    const size_t o0 = (size_t)n * DIMD + tid;
    dst[o0]       = f2bf((v0 - mu) * rs * (1.f + bf2f(mrow[scale_off + tid]))       + bf2f(mrow[shift_off + tid]));
    dst[o0 + 256] = f2bf((v1 - mu) * rs * (1.f + bf2f(mrow[scale_off + tid + 256])) + bf2f(mrow[shift_off + tid + 256]));
}

// ---------------------------------------------------------------------------
// MFMA flash attention v5: split-K flash-decoding. Uniform blocks of
// (64 q-rows x <=8 k-tiles). Grid (80, H, B): flat index f decodes (qi,ch)
// where qi = 64-row q group (0..31), ch = 8-tile k chunk. Each block writes
// a partial (O fp32 [64q][64d], m, l) to workspace; attn_combine merges.
// Inner math = verified R6 scheme (S^T = K·Q^T, per-lane softmax, exp2).
// LDS stride 76 (bank-conflict fix).
// ---------------------------------------------------------------------------
__global__ __launch_bounds__(256, 4) void attn_mfma(
    const unsigned short* __restrict__ qkv, float* __restrict__ part)
{
    __shared__ unsigned short Kt[64][76];     // K[kpos][d]
    __shared__ unsigned short Vt[64][76];     // V^T: Vt[d][kpos]
    __shared__ unsigned short Ps[4][16][76];  // per-wave P[q][kpos]

    const int f = 79 - (int)blockIdx.x;       // high-qi (4-chunk) blocks first
    int qi, ch;
    if (f < 8)       { qi = f;               ch = 0; }
    else if (f < 24) { const int g = f - 8;  qi = 8 + (g >> 1);  ch = g & 1; }
    else if (f < 48) { const int g = f - 24; qi = 16 + g / 3;    ch = g % 3; }
    else             { const int g = f - 48; qi = 24 + (g >> 2); ch = g & 3; }

    const int h = blockIdx.y, b = blockIdx.z;
    const int tid = threadIdx.x;
    const int w = tid >> 6;
    const int lane = tid & 63;
    const int quad = lane >> 4;
    const int l16 = lane & 15;

    const int qw = qi * 64 + w * 16;
    const size_t tokbase = (size_t)b * TT;

    // Q fragment (B operand of S^T = K·Q^T); log2(e)/8 folded in
    short8 qf[2];
    {
        const unsigned short* qp = qkv + (tokbase + qw + l16) * 1536 + h * 64 + quad * 8;
        #pragma unroll
        for (int hd = 0; hd < 2; hd++) {
            short8 raw = *(const short8*)(qp + hd * 32);
            short8 fr;
            #pragma unroll
            for (int j = 0; j < 8; j++)
                fr[j] = (short)f2bf(bf2f((unsigned short)raw[j]) * LOG2E_8);
            qf[hd] = fr;
        }
    }

    f32x4 Oa[4];   // col=l16=q, row=quad*4+r=d
    float mrun = -INFINITY, lrun = 0.f;
    #pragma unroll
    for (int mt = 0; mt < 4; mt++) Oa[mt] = (f32x4){0.f, 0.f, 0.f, 0.f};

    const int k0t = ch * 8;
    const int k1t = min(k0t + 8, qi + 1);
    const int vk0 = (tid & 31) * 2;
    const int vdb = (tid >> 5) * 8;

    short8 kpre[2], vpre[2];
    auto prefetchKV = [&](int kt) {
        const unsigned short* kb = qkv + (tokbase + (size_t)kt * 64) * 1536 + 512 + h * 64;
        #pragma unroll
        for (int it = 0; it < 2; it++) {
            const int i = tid + it * 256;
            kpre[it] = *(const short8*)(kb + (size_t)(i >> 3) * 1536 + (i & 7) * 8);
        }
        const unsigned short* vb = qkv + (tokbase + (size_t)kt * 64 + vk0) * 1536 + 1024 + h * 64 + vdb;
        vpre[0] = *(const short8*)vb;
        vpre[1] = *(const short8*)(vb + 1536);
    };
    auto storeKV = [&]() {
        #pragma unroll
        for (int it = 0; it < 2; it++) {
            const int i = tid + it * 256;
            *(short8*)&Kt[i >> 3][(i & 7) * 8] = kpre[it];
        }
        #pragma unroll
        for (int j = 0; j < 8; j++) {
            *(unsigned*)&Vt[vdb + j][vk0] =
                (unsigned)(unsigned short)vpre[0][j]
                | ((unsigned)(unsigned short)vpre[1][j] << 16);
        }
    };

    prefetchKV(k0t);
    storeKV();
    __syncthreads();

    for (int kt = k0t; kt < k1t; kt++) {
        const bool haveNext = (kt + 1 < k1t);
        if (haveNext) prefetchKV(kt + 1);

        // ---- S^T = K·Q^T ----
        f32x4 st[4];
        #pragma unroll
        for (int mk = 0; mk < 4; mk++) {
            const short8 a0 = *(const short8*)&Kt[mk * 16 + l16][quad * 8];
            const short8 a1 = *(const short8*)&Kt[mk * 16 + l16][32 + quad * 8];
            st[mk] = (f32x4){0.f, 0.f, 0.f, 0.f};
            st[mk] = mfma_bf16(a0, qf[0], st[mk]);
            st[mk] = mfma_bf16(a1, qf[1], st[mk]);
        }
        if (kt == qi) {   // diagonal tile
            const int qrel = w * 16 + l16;   // q within 64-row block
            #pragma unroll
            for (int mk = 0; mk < 4; mk++)
                #pragma unroll
                for (int r = 0; r < 4; r++)
                    if (mk * 16 + quad * 4 + r > qrel) st[mk][r] = -INFINITY;
        }
        // ---- per-lane softmax ----
        float tm = -INFINITY;
        #pragma unroll
        for (int mk = 0; mk < 4; mk++)
            #pragma unroll
            for (int r = 0; r < 4; r++) tm = fmaxf(tm, st[mk][r]);
        tm = fmaxf(tm, __shfl_xor(tm, 16));
        tm = fmaxf(tm, __shfl_xor(tm, 32));
        const float mn = fmaxf(mrun, tm);
        const float alpha = __builtin_amdgcn_exp2f(mrun - mn);
        mrun = mn;
        float ts = 0.f;
        #pragma unroll
        for (int mk = 0; mk < 4; mk++) {
            const float p0 = __builtin_amdgcn_exp2f(st[mk][0] - mn);
            const float p1 = __builtin_amdgcn_exp2f(st[mk][1] - mn);
            const float p2 = __builtin_amdgcn_exp2f(st[mk][2] - mn);
            const float p3 = __builtin_amdgcn_exp2f(st[mk][3] - mn);
            ts += (p0 + p1) + (p2 + p3);
            const unsigned long long pk =
                (unsigned long long)pk2bf(p0, p1)
                | ((unsigned long long)pk2bf(p2, p3) << 32);
            *(unsigned long long*)&Ps[w][l16][mk * 16 + quad * 4] = pk;
        }
        ts += __shfl_xor(ts, 16);
        ts += __shfl_xor(ts, 32);
        lrun = lrun * alpha + ts;
        #pragma unroll
        for (int mt = 0; mt < 4; mt++) Oa[mt] *= alpha;
        __threadfence_block();

        // ---- O^T += V^T·P^T ----
        short8 pf[2];
        #pragma unroll
        for (int kc = 0; kc < 2; kc++)
            pf[kc] = *(const short8*)&Ps[w][l16][kc * 32 + quad * 8];
        #pragma unroll
        for (int mt = 0; mt < 4; mt++)
            #pragma unroll
            for (int kc = 0; kc < 2; kc++) {
                const short8 vf = *(const short8*)&Vt[mt * 16 + l16][kc * 32 + quad * 8];
                Oa[mt] = mfma_bf16(vf, pf[kc], Oa[mt]);
            }

        __syncthreads();
        if (haveNext) storeKV();
        __syncthreads();
    }

    // ---- write partial: O [q][d] fp32, then (m,l) pairs ----
    float* pO = part + ((size_t)((b * HH + h) * 80 + f)) * PBLK;
    #pragma unroll
    for (int mt = 0; mt < 4; mt++)
        *(f32x4*)&pO[(w * 16 + l16) * 64 + mt * 16 + quad * 4] = Oa[mt];
    if (quad == 0) {
        pO[4096 + (w * 16 + l16) * 2]     = mrun;
        pO[4096 + (w * 16 + l16) * 2 + 1] = lrun;
    }
}

// ---------------------------------------------------------------------------
// Combine split-K partials: out = (sum_c e^{m_c-M} O_c) / (sum_c e^{m_c-M} l_c)
// Thread = (tok, h, 4-d group). m is in exp2 domain (consistent across chunks).
// ---------------------------------------------------------------------------
__global__ __launch_bounds__(256) void attn_combine(
    const float* __restrict__ part, unsigned short* __restrict__ outb)
{
    const int idx = blockIdx.x * 256 + threadIdx.x;
    const int d4 = idx & 15;
    const int h = (idx >> 4) & 7;
    const int tok = idx >> 7;
    const int t = tok & (TT - 1);
    const int b = tok >> 11;
    const int qi = t >> 6;
    const int nch = (qi >> 3) + 1;
    int cum;
    if (qi < 8)       cum = qi;
    else if (qi < 16) cum = 8 + ((qi - 8) << 1);
    else if (qi < 24) cum = 24 + (qi - 16) * 3;
    else              cum = 48 + ((qi - 24) << 2);
    const int qloc = t & 63;
    const float* base = part + ((size_t)((b * HH + h) * 80 + cum)) * PBLK;

    float M = -INFINITY;
    for (int c = 0; c < nch; c++)
        M = fmaxf(M, base[c * PBLK + 4096 + qloc * 2]);
    float L = 0.f, a0 = 0.f, a1 = 0.f, a2 = 0.f, a3 = 0.f;
    for (int c = 0; c < nch; c++) {
        const float m = base[c * PBLK + 4096 + qloc * 2];
        const float l = base[c * PBLK + 4097 + qloc * 2];
        const float sc = __builtin_amdgcn_exp2f(m - M);
        L += l * sc;
        const float4 o = *(const float4*)&base[c * PBLK + qloc * 64 + d4 * 4];
        a0 += sc * o.x; a1 += sc * o.y; a2 += sc * o.z; a3 += sc * o.w;
    }
    const float inv = 1.f / L;
    const unsigned long long pk =
        (unsigned long long)pk2bf(a0 * inv, a1 * inv)
        | ((unsigned long long)pk2bf(a2 * inv, a3 * inv) << 32);
    *(unsigned long long*)&outb[(size_t)tok * DIMD + h * 64 + d4 * 4] = pk;
}

// ---------------------------------------------------------------------------
extern "C" void kernel_launch(void* const* d_in, const int* in_sizes, int n_in,
                              void* d_out, int out_size, void* d_ws, size_t ws_size,
                              hipStream_t stream)
{
    (void)in_sizes; (void)n_in; (void)out_size; (void)ws_size;

    const float* x    = (const float*)d_in[0];
    const float* aemb = (const float*)d_in[1];
    const float* Wqkv = (const float*)d_in[3];
    const float* Wout = (const float*)d_in[4];
    const float* bout = (const float*)d_in[5];
    const float* W1   = (const float*)d_in[6];
    const float* b1   = (const float*)d_in[7];
    const float* W2   = (const float*)d_in[8];
    const float* b2   = (const float*)d_in[9];
    const float* Wmod = (const float*)d_in[10];
    const float* bmod = (const float*)d_in[11];

    float* out = (float*)d_out;

    // workspace layout
    char* p = (char*)d_ws;
    unsigned short* modw = (unsigned short*)p; p += (size_t)NTOK * MODD * 2;
    unsigned short* h12  = (unsigned short*)p; p += (size_t)NTOK * DIMD * 2;
    unsigned short* qkvb = (unsigned short*)p; p += (size_t)NTOK * 1536 * 2;
    unsigned short* attw = (unsigned short*)p; p += (size_t)NTOK * DIMD * 2;
    unsigned short* hid  = qkvb;        // reuses qkvb+attw
    unsigned short* sact = (unsigned short*)p; p += (size_t)NTOK * ADIMD * 2;
    unsigned short* wq = (unsigned short*)p;   p += (size_t)1536 * 512 * 2;
    unsigned short* wo = (unsigned short*)p;   p += (size_t)512 * 512 * 2;
    unsigned short* w1 = (unsigned short*)p;   p += (size_t)2048 * 512 * 2;
    unsigned short* w2 = (unsigned short*)p;   p += (size_t)512 * 2048 * 2;
    unsigned short* wm = (unsigned short*)p;   p += (size_t)3072 * 256 * 2;
    p = (char*)(((uintptr_t)p + 255) & ~(uintptr_t)255);
    float* part = (float*)p;                   // 32*80*PBLK*4 = 43.3 MB

    // 0) all dtype conversions in one launch
    CvtArgs ca;
    ca.s[0] = Wqkv; ca.d[0] = wq;
    ca.s[1] = Wout; ca.d[1] = wo;
    ca.s[2] = W1;   ca.d[2] = w1;
    ca.s[3] = W2;   ca.d[3] = w2;
    ca.s[4] = Wmod; ca.d[4] = wm;
    ca.s[5] = aemb; ca.d[5] = sact;
    const int n4s[6] = {1536 * 512 / 4, 512 * 512 / 4, 2048 * 512 / 4,
                        512 * 2048 / 4, 3072 * 256 / 4, NTOK * ADIMD / 4};
    ca.cum[0] = 0;
    for (int i = 0; i < 6; i++) ca.cum[i + 1] = ca.cum[i] + n4s[i];
    cvt_all<<<(ca.cum[6] + 255) / 256, 256, 0, stream>>>(ca);

    // 1) mod = silu(action_emb) @ Wmod^T + bmod  (bf16 out)
    gemm_bf16<5, 128><<<dim3(MODD / 128, NTOK / 128), 256, 0, stream>>>(
        sact, wm, bmod, nullptr, nullptr, NTOK, MODD, ADIMD, modw);

    // 2) h1 = LN(x)*(1+scale1)+shift1  (bf16 out)
    adaln_ln<<<NTOK, 256, 0, stream>>>(x, modw, h12, 0, 512);

    // 3) qkv = h1 @ Wqkv^T  (bf16 out)
    gemm_bf16<0, 128><<<dim3(1536 / 128, NTOK / 128), 256, 0, stream>>>(
        h12, wq, nullptr, nullptr, nullptr, NTOK, 1536, DIMD, qkvb);

    // 4) attention: split-K partials + combine
    attn_mfma<<<dim3(80, HH, BB), 256, 0, stream>>>(qkvb, part);
    attn_combine<<<NTOK * HH * 16 / 256, 256, 0, stream>>>(part, attw);

    // 5) x_mid = x + gate1 * (attw @ Wout^T + bout)  (fp32 out -> d_out)
    gemm_bf16<3, 64><<<dim3(DIMD / 64, NTOK / 128), 256, 0, stream>>>(
        attw, wo, bout, x, modw, NTOK, DIMD, DIMD, out);

    // 6) h2 = LN(x_mid)*(1+scale2)+shift2  (bf16 out)
    adaln_ln<<<NTOK, 256, 0, stream>>>(out, modw, h12, 1536, 2048);

    // 7) hid = gelu(h2 @ W1^T + b1)  (bf16 out)
    gemm_bf16<2, 128><<<dim3(MLPD / 128, NTOK / 128), 256, 0, stream>>>(
        h12, w1, b1, nullptr, nullptr, NTOK, MLPD, DIMD, hid);

    // 8) d_out = x_mid + gate2 * (hid @ W2^T + b2)  (fp32 RMW)
    gemm_bf16<4, 64><<<dim3(DIMD / 64, NTOK / 128), 256, 0, stream>>>(
        hid, w2, b2, nullptr, modw, NTOK, DIMD, MLPD, out);
}